// Round 1
// baseline (338.671 us; speedup 1.0000x reference)
//
#include <hip/hip_runtime.h>
#include <stdint.h>

typedef unsigned short u16;
typedef unsigned int u32;
typedef __attribute__((ext_vector_type(8))) short short8;
typedef __attribute__((ext_vector_type(4))) short short4v;
typedef __attribute__((ext_vector_type(4))) float f32x4;

#define HW 64
#define CH 256
#define NIMG 16
#define NPIX (NIMG*HW*HW)   // 65536 pixels

static __device__ __forceinline__ u16 f2bf(float f){
  u32 u = __float_as_uint(f);
  u32 r = u + 0x7FFFu + ((u >> 16) & 1u);   // RNE
  return (u16)(r >> 16);
}
static __device__ __forceinline__ float bf2f(u16 h){
  return __uint_as_float(((u32)h) << 16);
}
static __device__ __forceinline__ u32 relu_pk(u32 w){   // relu two packed bf16
  u32 lo = (w & 0x00008000u) ? 0u : (w & 0x0000FFFFu);
  u32 hi = (w & 0x80000000u) ? 0u : (w & 0xFFFF0000u);
  return lo | hi;
}

// ---------------- weight prep: W1T[j][c], W2T[j][tap][c], bf16 ----------------
__global__ void k_prep(const float* __restrict__ w1, const float* __restrict__ w2,
                       u16* __restrict__ W1T, u16* __restrict__ W2T){
  int idx = blockIdx.x*256 + threadIdx.x;   // 640*256 = 163840 exactly
  if (idx < 16384){
    int j = idx >> 8, c = idx & 255;
    W1T[idx] = f2bf(w1[c*64 + j]);          // w1 is (1,1,256,64) -> [c][j]
  } else {
    int o = idx - 16384;
    int j = o / 2304;
    int rem = o - j*2304;
    int tap = rem >> 8, c = rem & 255;
    W2T[o] = f2bf(w2[(tap*256 + c)*64 + j]); // w2 is (3,3,256,64) -> [tap][c][j]
  }
}

// ---------------- phase 1: fused 4-step pointwise gradual update ----------------
// pointwise => per-pixel independent; keep 128-px tile in LDS, update in place.
__global__ __launch_bounds__(256) void k_phase1(const float* __restrict__ x,
    const u16* __restrict__ W1T, const float* __restrict__ b1, u16* __restrict__ B){
  __shared__ u16 At[128*264];   // 128 px x 256 ch (+8 pad), bf16
  __shared__ u16 Ws[64*264];    // W1T staged [n][k] (+8 pad)
  const int tid = threadIdx.x;
  const long pbase = (long)blockIdx.x * 128;

  #pragma unroll
  for (int it=0; it<32; ++it){
    int idx = it*256 + tid;
    int px = idx >> 6;
    int c4 = (idx & 63) << 2;
    const float4 v = *(const float4*)(x + (pbase + px)*CH + c4);
    short4v s;
    s[0] = (short)f2bf(v.x); s[1] = (short)f2bf(v.y);
    s[2] = (short)f2bf(v.z); s[3] = (short)f2bf(v.w);
    *(short4v*)&At[px*264 + c4] = s;
  }
  #pragma unroll
  for (int it=0; it<8; ++it){
    int idx = it*256 + tid;
    int n = idx >> 5;
    int c8 = (idx & 31) << 3;
    *(uint4*)&Ws[n*264 + c8] = *(const uint4*)&W1T[n*256 + c8];
  }
  __syncthreads();

  const int wave = tid >> 6, lane = tid & 63;
  const int m = lane & 15, quad = lane >> 4;
  int abase[2], bbase[4];
  #pragma unroll
  for (int mt=0; mt<2; ++mt) abase[mt] = (wave*32 + mt*16 + m)*264 + quad*8;
  #pragma unroll
  for (int nt=0; nt<4; ++nt) bbase[nt] = (nt*16 + m)*264 + quad*8;
  float b1v[4];
  #pragma unroll
  for (int nt=0; nt<4; ++nt) b1v[nt] = b1[nt*16 + m];

  // 4 dependent steps; each wave reads/writes only its own pixel rows -> no barriers
  for (int stepi=0; stepi<4; ++stepi){
    f32x4 acc[2][4];
    #pragma unroll
    for (int a=0;a<2;++a){
      #pragma unroll
      for (int b=0;b<4;++b) acc[a][b] = 0.f;
    }
    #pragma unroll
    for (int kk=0; kk<8; ++kk){
      const int ko = kk*32;
      short8 af[2], bf[4];
      #pragma unroll
      for (int mt=0; mt<2; ++mt) af[mt] = *(const short8*)&At[abase[mt] + ko];
      #pragma unroll
      for (int nt=0; nt<4; ++nt) bf[nt] = *(const short8*)&Ws[bbase[nt] + ko];
      #pragma unroll
      for (int mt=0; mt<2; ++mt){
        #pragma unroll
        for (int nt=0; nt<4; ++nt)
          acc[mt][nt] = __builtin_amdgcn_mfma_f32_16x16x32_bf16(af[mt], bf[nt], acc[mt][nt], 0,0,0);
      }
    }
    #pragma unroll
    for (int mt=0; mt<2; ++mt){
      #pragma unroll
      for (int nt=0; nt<4; ++nt){
        #pragma unroll
        for (int r=0; r<4; ++r){
          int px = wave*32 + mt*16 + quad*4 + r;
          At[px*264 + stepi*64 + nt*16 + m] = f2bf(acc[mt][nt][r] + b1v[nt]);
        }
      }
    }
  }
  __syncthreads();
  #pragma unroll
  for (int it=0; it<32; ++it){
    int idx = it*256 + tid;
    int px = idx >> 6;
    int c4 = (idx & 63) << 2;
    *(uint2*)&B[(pbase + px)*CH + c4] = *(const uint2*)&At[px*264 + c4];
  }
}

// ---------------- phase 2: one 3x3 gradual-update step (launched 4x) ----------------
// reads blocks >= step from B (relu'd), blocks < step from Bout (raw); writes block `step` to Bout.
__global__ __launch_bounds__(256) void k_phase2(const u16* __restrict__ B,
    u16* __restrict__ Bout, const u16* __restrict__ W2T, const float* __restrict__ b2,
    const int step){
  __shared__ u16 As[340*136];  // 10x34 halo px x 128 ch (+8 pad)
  __shared__ u16 Ws[64*136];   // one tap, one K-half: [n][k]
  const int tid = threadIdx.x;
  const int bid = blockIdx.x;
  const int n = bid >> 4;
  const int t_id = bid & 15;
  const int R0 = (t_id >> 1) * 8;    // 8-row tile
  const int C0 = (t_id & 1) * 32;    // 32-col tile

  const int wave = tid >> 6, lane = tid & 63;
  const int m = lane & 15, quad = lane >> 4;
  int abase[4], bbase[4];
  #pragma unroll
  for (int mt=0; mt<4; ++mt){
    int pxl = wave*64 + mt*16 + m;
    abase[mt] = ((pxl >> 5) * 34 + (pxl & 31)) * 136 + quad*8;
  }
  #pragma unroll
  for (int nt=0; nt<4; ++nt) bbase[nt] = (nt*16 + m)*136 + quad*8;

  f32x4 acc[4][4];
  #pragma unroll
  for (int a=0;a<4;++a){
    #pragma unroll
    for (int b=0;b<4;++b) acc[a][b] = 0.f;
  }

  for (int half=0; half<2; ++half){
    __syncthreads();
    // stage halo'd activations for this K-half (340 px x 16 chunks = 5440)
    for (int it=0; it<22; ++it){
      int idx = it*256 + tid;
      if (idx < 5440){
        int px = idx >> 4;
        int ch8 = (idx & 15) << 3;
        int prh = px / 34;
        int pch = px - prh*34;
        int r_img = R0 + prh - 1;
        int c_img = C0 + pch - 1;
        uint4 v = make_uint4(0,0,0,0);
        int cg = half*128 + ch8;
        if ((unsigned)r_img < 64u && (unsigned)c_img < 64u){
          long gi = ((((long)n*64 + r_img)*64) + c_img)*CH + cg;
          if ((cg >> 6) < step){
            v = *(const uint4*)&Bout[gi];
          } else {
            v = *(const uint4*)&B[gi];
            v.x = relu_pk(v.x); v.y = relu_pk(v.y); v.z = relu_pk(v.z); v.w = relu_pk(v.w);
          }
        }
        *(uint4*)&As[px*136 + ch8] = v;
      }
    }
    for (int tap=0; tap<9; ++tap){
      __syncthreads();
      #pragma unroll
      for (int it=0; it<4; ++it){
        int idx = it*256 + tid;
        int nn = idx >> 4;
        int ch8 = (idx & 15) << 3;
        *(uint4*)&Ws[nn*136 + ch8] = *(const uint4*)&W2T[(nn*9 + tap)*256 + half*128 + ch8];
      }
      __syncthreads();
      const int toff = ((tap/3)*34 + (tap - (tap/3)*3)) * 136;
      #pragma unroll
      for (int kk=0; kk<4; ++kk){
        const int ko = kk*32;
        short8 af[4], bf[4];
        #pragma unroll
        for (int mt=0; mt<4; ++mt) af[mt] = *(const short8*)&As[abase[mt] + toff + ko];
        #pragma unroll
        for (int nt=0; nt<4; ++nt) bf[nt] = *(const short8*)&Ws[bbase[nt] + ko];
        #pragma unroll
        for (int mt=0; mt<4; ++mt){
          #pragma unroll
          for (int nt=0; nt<4; ++nt)
            acc[mt][nt] = __builtin_amdgcn_mfma_f32_16x16x32_bf16(af[mt], bf[nt], acc[mt][nt], 0,0,0);
        }
      }
    }
  }
  float b2v[4];
  #pragma unroll
  for (int nt=0; nt<4; ++nt) b2v[nt] = b2[nt*16 + m];
  #pragma unroll
  for (int mt=0; mt<4; ++mt){
    #pragma unroll
    for (int nt=0; nt<4; ++nt){
      #pragma unroll
      for (int r=0; r<4; ++r){
        int pxl = wave*64 + mt*16 + quad*4 + r;
        int prr = pxl >> 5, pcc = pxl & 31;
        long gi = ((((long)n*64 + R0 + prr)*64) + C0 + pcc)*CH + step*64 + nt*16 + m;
        Bout[gi] = f2bf(acc[mt][nt][r] + b2v[nt]);
      }
    }
  }
}

// ---------------- phase 3: per-pixel affine recurrence + residual ----------------
// A'_0 = b3 + sum_c a_c w_c ;  A'_{i+1} = A'_i + w_i*(A'_i - a_i) ; out_i = A'_i + x_i
__global__ __launch_bounds__(256) void k_phase3(const u16* __restrict__ Bout,
    const float* __restrict__ w3, const float* __restrict__ b3,
    const float* __restrict__ x, float* __restrict__ out){
  __shared__ u16 A3[256*264];
  __shared__ float w3s[256];
  const int tid = threadIdx.x;
  const long pbase = (long)blockIdx.x * 256;

  #pragma unroll
  for (int it=0; it<32; ++it){
    int idx = it*256 + tid;
    int px = idx >> 5;
    int ch8 = (idx & 31) << 3;
    uint4 v = *(const uint4*)&Bout[(pbase + px)*CH + ch8];
    v.x = relu_pk(v.x); v.y = relu_pk(v.y); v.z = relu_pk(v.z); v.w = relu_pk(v.w);
    *(uint4*)&A3[px*264 + ch8] = v;
  }
  if (tid < 64) *(float4*)&w3s[tid*4] = *(const float4*)&w3[tid*4];
  const float b3v = b3[0];
  __syncthreads();

  const int base = tid*264;           // thread == pixel within tile
  float acc = b3v;
  for (int c8=0; c8<32; ++c8){
    short8 a = *(const short8*)&A3[base + c8*8];
    #pragma unroll
    for (int k2=0; k2<8; ++k2)
      acc += bf2f((u16)a[k2]) * w3s[c8*8 + k2];
  }
  float Ap = acc;
  for (int c8=0; c8<32; ++c8){
    short8 a = *(const short8*)&A3[base + c8*8];
    short8 o;
    #pragma unroll
    for (int k2=0; k2<8; ++k2){
      o[k2] = (short)f2bf(Ap);        // emit A'_i
      float av = bf2f((u16)a[k2]);
      float w  = w3s[c8*8 + k2];
      Ap = Ap + w * (Ap - av);        // -> A'_{i+1}
    }
    *(short8*)&A3[base + c8*8] = o;   // overwrite own row in place
  }
  __syncthreads();

  #pragma unroll
  for (int it=0; it<32; ++it){
    int idx = it*256 + tid;
    int px = idx >> 5;
    int ch8 = (idx & 31) << 3;
    short8 a = *(const short8*)&A3[px*264 + ch8];
    long g = (pbase + px)*CH + ch8;
    const float4 x1 = *(const float4*)&x[g];
    const float4 x2 = *(const float4*)&x[g + 4];
    float4 o1, o2;
    o1.x = bf2f((u16)a[0]) + x1.x;
    o1.y = bf2f((u16)a[1]) + x1.y;
    o1.z = bf2f((u16)a[2]) + x1.z;
    o1.w = bf2f((u16)a[3]) + x1.w;
    o2.x = bf2f((u16)a[4]) + x2.x;
    o2.y = bf2f((u16)a[5]) + x2.y;
    o2.z = bf2f((u16)a[6]) + x2.z;
    o2.w = bf2f((u16)a[7]) + x2.w;
    *(float4*)&out[g]     = o1;
    *(float4*)&out[g + 4] = o2;
  }
}

extern "C" void kernel_launch(void* const* d_in, const int* in_sizes, int n_in,
                              void* d_out, int out_size, void* d_ws, size_t ws_size,
                              hipStream_t stream){
  const float* x  = (const float*)d_in[0];
  const float* w1 = (const float*)d_in[1];
  const float* b1 = (const float*)d_in[2];
  const float* w2 = (const float*)d_in[3];
  const float* b2 = (const float*)d_in[4];
  const float* w3 = (const float*)d_in[5];
  const float* b3 = (const float*)d_in[6];
  float* out = (float*)d_out;

  // workspace carve (bytes): B 32MB | Bout 32MB | W1T 32KB | W2T 288KB
  u16* B    = (u16*)d_ws;
  u16* Bout = B    + (size_t)NPIX*CH;
  u16* W1T  = Bout + (size_t)NPIX*CH;
  u16* W2T  = W1T  + 16384;

  hipLaunchKernelGGL(k_prep,   dim3(640), dim3(256), 0, stream, w1, w2, W1T, W2T);
  hipLaunchKernelGGL(k_phase1, dim3(512), dim3(256), 0, stream, x, W1T, b1, B);
  for (int s = 0; s < 4; ++s)
    hipLaunchKernelGGL(k_phase2, dim3(256), dim3(256), 0, stream, B, Bout, W2T, b2, s);
  hipLaunchKernelGGL(k_phase3, dim3(256), dim3(256), 0, stream, Bout, w3, b3, x, out);
}

// Round 2
// 330.749 us; speedup vs baseline: 1.0240x; 1.0240x over previous
//
#include <hip/hip_runtime.h>
#include <stdint.h>

typedef unsigned short u16;
typedef unsigned int u32;
typedef __attribute__((ext_vector_type(8))) short short8;
typedef __attribute__((ext_vector_type(4))) short short4v;
typedef __attribute__((ext_vector_type(4))) float f32x4;

#define HW 64
#define CH 256
#define NIMG 16
#define NPIX (NIMG*HW*HW)   // 65536 pixels

static __device__ __forceinline__ u16 f2bf(float f){
  u32 u = __float_as_uint(f);
  u32 r = u + 0x7FFFu + ((u >> 16) & 1u);   // RNE
  return (u16)(r >> 16);
}
static __device__ __forceinline__ float bf2f(u16 h){
  return __uint_as_float(((u32)h) << 16);
}
static __device__ __forceinline__ u32 relu_pk(u32 w){   // relu two packed bf16
  u32 lo = (w & 0x00008000u) ? 0u : (w & 0x0000FFFFu);
  u32 hi = (w & 0x80000000u) ? 0u : (w & 0xFFFF0000u);
  return lo | hi;
}

// ---------------- weight prep: W1T[j][c], W2T[j][tap][c], bf16 ----------------
__global__ void k_prep(const float* __restrict__ w1, const float* __restrict__ w2,
                       u16* __restrict__ W1T, u16* __restrict__ W2T){
  int idx = blockIdx.x*256 + threadIdx.x;   // 640*256 = 163840 exactly
  if (idx < 16384){
    int j = idx >> 8, c = idx & 255;
    W1T[idx] = f2bf(w1[c*64 + j]);          // w1 is (1,1,256,64) -> [c][j]
  } else {
    int o = idx - 16384;
    int j = o / 2304;
    int rem = o - j*2304;
    int tap = rem >> 8, c = rem & 255;
    W2T[o] = f2bf(w2[(tap*256 + c)*64 + j]); // w2 is (3,3,256,64) -> [tap][c][j]
  }
}

// ---------------- phase 1: fused 4-step pointwise gradual update ----------------
// writes B = relu(final A) so phase-2 staging is a pure copy.
__global__ __launch_bounds__(256) void k_phase1(const float* __restrict__ x,
    const u16* __restrict__ W1T, const float* __restrict__ b1, u16* __restrict__ B){
  __shared__ u16 At[128*264];   // 128 px x 256 ch (+8 pad), bf16
  __shared__ u16 Ws[64*264];    // W1T staged [n][k] (+8 pad)
  const int tid = threadIdx.x;
  const long pbase = (long)blockIdx.x * 128;

  #pragma unroll
  for (int it=0; it<32; ++it){
    int idx = it*256 + tid;
    int px = idx >> 6;
    int c4 = (idx & 63) << 2;
    const float4 v = *(const float4*)(x + (pbase + px)*CH + c4);
    short4v s;
    s[0] = (short)f2bf(v.x); s[1] = (short)f2bf(v.y);
    s[2] = (short)f2bf(v.z); s[3] = (short)f2bf(v.w);
    *(short4v*)&At[px*264 + c4] = s;
  }
  #pragma unroll
  for (int it=0; it<8; ++it){
    int idx = it*256 + tid;
    int n = idx >> 5;
    int c8 = (idx & 31) << 3;
    *(uint4*)&Ws[n*264 + c8] = *(const uint4*)&W1T[n*256 + c8];
  }
  __syncthreads();

  const int wave = tid >> 6, lane = tid & 63;
  const int m = lane & 15, quad = lane >> 4;
  int abase[2], bbase[4];
  #pragma unroll
  for (int mt=0; mt<2; ++mt) abase[mt] = (wave*32 + mt*16 + m)*264 + quad*8;
  #pragma unroll
  for (int nt=0; nt<4; ++nt) bbase[nt] = (nt*16 + m)*264 + quad*8;
  float b1v[4];
  #pragma unroll
  for (int nt=0; nt<4; ++nt) b1v[nt] = b1[nt*16 + m];

  for (int stepi=0; stepi<4; ++stepi){
    f32x4 acc[2][4];
    #pragma unroll
    for (int a=0;a<2;++a){
      #pragma unroll
      for (int b=0;b<4;++b) acc[a][b] = 0.f;
    }
    #pragma unroll
    for (int kk=0; kk<8; ++kk){
      const int ko = kk*32;
      short8 af[2], bf[4];
      #pragma unroll
      for (int mt=0; mt<2; ++mt) af[mt] = *(const short8*)&At[abase[mt] + ko];
      #pragma unroll
      for (int nt=0; nt<4; ++nt) bf[nt] = *(const short8*)&Ws[bbase[nt] + ko];
      #pragma unroll
      for (int mt=0; mt<2; ++mt){
        #pragma unroll
        for (int nt=0; nt<4; ++nt)
          acc[mt][nt] = __builtin_amdgcn_mfma_f32_16x16x32_bf16(af[mt], bf[nt], acc[mt][nt], 0,0,0);
      }
    }
    #pragma unroll
    for (int mt=0; mt<2; ++mt){
      #pragma unroll
      for (int nt=0; nt<4; ++nt){
        #pragma unroll
        for (int r=0; r<4; ++r){
          int px = wave*32 + mt*16 + quad*4 + r;
          At[px*264 + stepi*64 + nt*16 + m] = f2bf(acc[mt][nt][r] + b1v[nt]);
        }
      }
    }
  }
  __syncthreads();
  #pragma unroll
  for (int it=0; it<32; ++it){
    int idx = it*256 + tid;
    int px = idx >> 6;
    int c4 = (idx & 63) << 2;
    uint2 v = *(const uint2*)&At[px*264 + c4];
    v.x = relu_pk(v.x); v.y = relu_pk(v.y);
    *(uint2*)&B[(pbase + px)*CH + c4] = v;
  }
}

// ---------------- phase 2: one 3x3 gradual-update step (launched 4x) ----------------
// 16x16 px tiles, 256 blocks, 4 waves. K split in 64-ch quarters (== gradual blocks).
// Double-buffered As (per quarter) and Ws (per tap-row dr). Prefetch: global->regs at
// segment start, regs->LDS after compute, 1 barrier per segment (13 total vs 38 before).
#define AS_STRIDE 72
#define WS_STRIDE 72

__global__ __launch_bounds__(256) void k_phase2(const u16* __restrict__ B,
    u16* __restrict__ Bout, const u16* __restrict__ W2T, const float* __restrict__ b2,
    const int step){
  __shared__ u16 As[2][324*AS_STRIDE];   // 18x18 halo px x 64 ch (+8 pad)  2x46.7KB
  __shared__ u16 Ws[2][192*WS_STRIDE];   // 3 taps x 64 n x 64 ch (+8 pad) 2x27.6KB
  const int tid = threadIdx.x;
  const int bid = blockIdx.x;
  const int img = bid >> 4;
  const int R0 = ((bid >> 2) & 3) * 16;
  const int C0 = (bid & 3) * 16;

  const int wave = tid >> 6, lane = tid & 63;
  const int m = lane & 15, quad = lane >> 4;

  auto load_as = [&](int q, uint4* regs){
    #pragma unroll
    for (int it=0; it<11; ++it){
      int idx = it*256 + tid;
      int px = idx >> 3, chunk = idx & 7;
      uint4 v = make_uint4(0u,0u,0u,0u);
      if (px < 324){
        int hr = px / 18, hc = px - hr*18;
        int r_img = R0 + hr - 1, c_img = C0 + hc - 1;
        if ((unsigned)r_img < 64u && (unsigned)c_img < 64u){
          const u16* src = (q < step) ? (const u16*)Bout : B;
          size_t gi = ((((size_t)img*64 + r_img)*64) + c_img)*CH + q*64 + chunk*8;
          v = *(const uint4*)&src[gi];
        }
      }
      regs[it] = v;
    }
  };
  auto store_as = [&](int buf, const uint4* regs){
    #pragma unroll
    for (int it=0; it<11; ++it){
      int idx = it*256 + tid;
      int px = idx >> 3, chunk = idx & 7;
      if (px < 324) *(uint4*)&As[buf][px*AS_STRIDE + chunk*8] = regs[it];
    }
  };
  auto load_ws = [&](int q, int dr, uint4* regs){
    #pragma unroll
    for (int it=0; it<6; ++it){
      int idx = it*256 + tid;
      int row = idx >> 3, chunk = idx & 7;     // row = dc*64 + n
      int dc = row >> 6, n = row & 63;
      regs[it] = *(const uint4*)&W2T[(size_t)n*2304 + (dr*3 + dc)*256 + q*64 + chunk*8];
    }
  };
  auto store_ws = [&](int buf, const uint4* regs){
    #pragma unroll
    for (int it=0; it<6; ++it){
      int idx = it*256 + tid;
      int row = idx >> 3, chunk = idx & 7;
      *(uint4*)&Ws[buf][row*WS_STRIDE + chunk*8] = regs[it];
    }
  };

  // prologue: stage quarter 0 activations + (q=0, dr=0) weights
  {
    uint4 ra[11]; load_as(0, ra); store_as(0, ra);
    uint4 rw[6];  load_ws(0, 0, rw); store_ws(0, rw);
  }
  __syncthreads();

  f32x4 acc[4][4];
  #pragma unroll
  for (int a=0;a<4;++a){
    #pragma unroll
    for (int b=0;b<4;++b) acc[a][b] = 0.f;
  }

  int seg = 0;
  for (int q = 0; q < 4; ++q){
    uint4 asr[11];
    const int ab = q & 1;
    for (int dr = 0; dr < 3; ++dr, ++seg){
      const int wb = seg & 1;
      uint4 wsr[6];
      const bool haveWs = (dr < 2) || (q < 3);
      // issue prefetch loads early (results consumed only after compute)
      if (dr < 2)      load_ws(q, dr+1, wsr);
      else if (q < 3)  load_ws(q+1, 0, wsr);
      if (dr == 0 && q < 3) load_as(q+1, asr);

      const u16* asb = As[ab];
      const u16* wsb = Ws[wb];
      #pragma unroll
      for (int dc=0; dc<3; ++dc){
        #pragma unroll
        for (int kk=0; kk<2; ++kk){
          short8 af[4], bf[4];
          #pragma unroll
          for (int mt=0; mt<4; ++mt){
            int px = (wave*4 + mt + dr)*18 + (m + dc);
            af[mt] = *(const short8*)&asb[px*AS_STRIDE + kk*32 + quad*8];
          }
          #pragma unroll
          for (int nt=0; nt<4; ++nt)
            bf[nt] = *(const short8*)&wsb[(dc*64 + nt*16 + m)*WS_STRIDE + kk*32 + quad*8];
          #pragma unroll
          for (int mt=0; mt<4; ++mt){
            #pragma unroll
            for (int nt=0; nt<4; ++nt)
              acc[mt][nt] = __builtin_amdgcn_mfma_f32_16x16x32_bf16(af[mt], bf[nt], acc[mt][nt], 0,0,0);
          }
        }
      }
      // commit prefetched data to the alternate buffers
      if (haveWs) store_ws(wb^1, wsr);
      if (dr == 2 && q < 3) store_as(ab^1, asr);
      __syncthreads();
    }
  }

  float b2v[4];
  #pragma unroll
  for (int nt=0; nt<4; ++nt) b2v[nt] = b2[nt*16 + m];
  #pragma unroll
  for (int mt=0; mt<4; ++mt){
    #pragma unroll
    for (int nt=0; nt<4; ++nt){
      #pragma unroll
      for (int r=0; r<4; ++r){
        int row = R0 + wave*4 + mt;
        int col = C0 + quad*4 + r;
        size_t gi = ((((size_t)img*64 + row)*64) + col)*CH + step*64 + nt*16 + m;
        Bout[gi] = f2bf(acc[mt][nt][r] + b2v[nt]);
      }
    }
  }
}

// ---------------- phase 3: per-pixel affine recurrence + residual ----------------
// A'_0 = b3 + sum_c a_c w_c ;  A'_{i+1} = A'_i + w_i*(A'_i - a_i) ; out_i = A'_i + x_i
__global__ __launch_bounds__(256) void k_phase3(const u16* __restrict__ Bout,
    const float* __restrict__ w3, const float* __restrict__ b3,
    const float* __restrict__ x, float* __restrict__ out){
  __shared__ u16 A3[256*260];   // stride 260 u16 = 130 dw (==2 mod 32): 2-way max on b64
  __shared__ float w3s[256];
  const int tid = threadIdx.x;
  const long pbase = (long)blockIdx.x * 256;

  #pragma unroll
  for (int it=0; it<32; ++it){
    int idx = it*256 + tid;
    int px = idx >> 5;
    int ch8 = (idx & 31) << 3;
    uint4 v = *(const uint4*)&Bout[(pbase + px)*CH + ch8];
    v.x = relu_pk(v.x); v.y = relu_pk(v.y); v.z = relu_pk(v.z); v.w = relu_pk(v.w);
    uint2 lo, hi;
    lo.x = v.x; lo.y = v.y; hi.x = v.z; hi.y = v.w;
    *(uint2*)&A3[px*260 + ch8]     = lo;
    *(uint2*)&A3[px*260 + ch8 + 4] = hi;
  }
  if (tid < 64) *(float4*)&w3s[tid*4] = *(const float4*)&w3[tid*4];
  const float b3v = b3[0];
  __syncthreads();

  const int base = tid*260;           // thread == pixel within tile
  float acc = b3v;
  for (int c4=0; c4<64; ++c4){
    short4v a = *(const short4v*)&A3[base + c4*4];
    #pragma unroll
    for (int j=0; j<4; ++j)
      acc += bf2f((u16)a[j]) * w3s[c4*4 + j];
  }
  float Ap = acc;
  for (int c4=0; c4<64; ++c4){
    short4v a = *(const short4v*)&A3[base + c4*4];
    short4v o;
    #pragma unroll
    for (int j=0; j<4; ++j){
      o[j] = (short)f2bf(Ap);         // emit A'_i
      float av = bf2f((u16)a[j]);
      Ap = Ap + w3s[c4*4 + j] * (Ap - av);
    }
    *(short4v*)&A3[base + c4*4] = o;
  }
  __syncthreads();

  #pragma unroll
  for (int it=0; it<32; ++it){
    int idx = it*256 + tid;
    int px = idx >> 5;
    int ch8 = (idx & 31) << 3;
    short4v a0 = *(const short4v*)&A3[px*260 + ch8];
    short4v a1 = *(const short4v*)&A3[px*260 + ch8 + 4];
    long g = (pbase + px)*CH + ch8;
    const float4 x1 = *(const float4*)&x[g];
    const float4 x2 = *(const float4*)&x[g + 4];
    float4 o1, o2;
    o1.x = bf2f((u16)a0[0]) + x1.x;
    o1.y = bf2f((u16)a0[1]) + x1.y;
    o1.z = bf2f((u16)a0[2]) + x1.z;
    o1.w = bf2f((u16)a0[3]) + x1.w;
    o2.x = bf2f((u16)a1[0]) + x2.x;
    o2.y = bf2f((u16)a1[1]) + x2.y;
    o2.z = bf2f((u16)a1[2]) + x2.z;
    o2.w = bf2f((u16)a1[3]) + x2.w;
    *(float4*)&out[g]     = o1;
    *(float4*)&out[g + 4] = o2;
  }
}

extern "C" void kernel_launch(void* const* d_in, const int* in_sizes, int n_in,
                              void* d_out, int out_size, void* d_ws, size_t ws_size,
                              hipStream_t stream){
  const float* x  = (const float*)d_in[0];
  const float* w1 = (const float*)d_in[1];
  const float* b1 = (const float*)d_in[2];
  const float* w2 = (const float*)d_in[3];
  const float* b2 = (const float*)d_in[4];
  const float* w3 = (const float*)d_in[5];
  const float* b3 = (const float*)d_in[6];
  float* out = (float*)d_out;

  // workspace carve: B(relu'd) 32MB | Bout 32MB | W1T 32KB | W2T 288KB
  u16* B    = (u16*)d_ws;
  u16* Bout = B    + (size_t)NPIX*CH;
  u16* W1T  = Bout + (size_t)NPIX*CH;
  u16* W2T  = W1T  + 16384;

  hipLaunchKernelGGL(k_prep,   dim3(640), dim3(256), 0, stream, w1, w2, W1T, W2T);
  hipLaunchKernelGGL(k_phase1, dim3(512), dim3(256), 0, stream, x, W1T, b1, B);
  for (int s = 0; s < 4; ++s)
    hipLaunchKernelGGL(k_phase2, dim3(256), dim3(256), 0, stream, B, Bout, W2T, b2, s);
  hipLaunchKernelGGL(k_phase3, dim3(256), dim3(256), 0, stream, Bout, w3, b3, x, out);
}

// Round 3
// 318.201 us; speedup vs baseline: 1.0643x; 1.0394x over previous
//
#include <hip/hip_runtime.h>
#include <stdint.h>

typedef unsigned short u16;
typedef unsigned int u32;
typedef __attribute__((ext_vector_type(8))) short short8;
typedef __attribute__((ext_vector_type(4))) short short4v;
typedef __attribute__((ext_vector_type(4))) float f32x4;

#define HW 64
#define CH 256
#define NIMG 16
#define NPIX (NIMG*HW*HW)   // 65536 pixels

static __device__ __forceinline__ u16 f2bf(float f){
  u32 u = __float_as_uint(f);
  u32 r = u + 0x7FFFu + ((u >> 16) & 1u);   // RNE
  return (u16)(r >> 16);
}
static __device__ __forceinline__ float bf2f(u16 h){
  return __uint_as_float(((u32)h) << 16);
}
static __device__ __forceinline__ u32 relu_pk(u32 w){   // relu two packed bf16
  u32 lo = (w & 0x00008000u) ? 0u : (w & 0x0000FFFFu);
  u32 hi = (w & 0x80000000u) ? 0u : (w & 0xFFFF0000u);
  return lo | hi;
}

// ---------------- weight prep: W1T[j][c], W2T[j][tap][c], bf16 ----------------
__global__ void k_prep(const float* __restrict__ w1, const float* __restrict__ w2,
                       u16* __restrict__ W1T, u16* __restrict__ W2T){
  int idx = blockIdx.x*256 + threadIdx.x;   // 640*256 = 163840 exactly
  if (idx < 16384){
    int j = idx >> 8, c = idx & 255;
    W1T[idx] = f2bf(w1[c*64 + j]);          // w1 is (1,1,256,64) -> [c][j]
  } else {
    int o = idx - 16384;
    int j = o / 2304;
    int rem = o - j*2304;
    int tap = rem >> 8, c = rem & 255;
    W2T[o] = f2bf(w2[(tap*256 + c)*64 + j]); // w2 is (3,3,256,64) -> [tap][c][j]
  }
}

// ---------------- phase 1: fused 4-step pointwise gradual update ----------------
// 64-px tiles (grid 1024), LDS 66 KB -> 2 blocks/CU resident = 2 waves/SIMD.
// Wave owns 16 px (mt=1, nt=4): step updates are wave-private, no inter-step barrier.
// Writes B = relu(final A).
__global__ __launch_bounds__(256) void k_phase1(const float* __restrict__ x,
    const u16* __restrict__ W1T, const float* __restrict__ b1, u16* __restrict__ B){
  __shared__ u16 At[64*264];    // 64 px x 256 ch (+8 pad)  33792 B
  __shared__ u16 Ws[64*264];    // W1T staged [n][k] (+8)   33792 B
  const int tid = threadIdx.x;
  const long pbase = (long)blockIdx.x * 64;

  #pragma unroll
  for (int it=0; it<16; ++it){
    int idx = it*256 + tid;
    int px = idx >> 6;
    int c4 = (idx & 63) << 2;
    const float4 v = *(const float4*)(x + (pbase + px)*CH + c4);
    short4v s;
    s[0] = (short)f2bf(v.x); s[1] = (short)f2bf(v.y);
    s[2] = (short)f2bf(v.z); s[3] = (short)f2bf(v.w);
    *(short4v*)&At[px*264 + c4] = s;
  }
  #pragma unroll
  for (int it=0; it<8; ++it){
    int idx = it*256 + tid;
    int n = idx >> 5;
    int c8 = (idx & 31) << 3;
    *(uint4*)&Ws[n*264 + c8] = *(const uint4*)&W1T[n*256 + c8];
  }
  __syncthreads();

  const int wave = tid >> 6, lane = tid & 63;
  const int m = lane & 15, quad = lane >> 4;
  const int abase = (wave*16 + m)*264 + quad*8;
  int bbase[4];
  #pragma unroll
  for (int nt=0; nt<4; ++nt) bbase[nt] = (nt*16 + m)*264 + quad*8;
  float b1v[4];
  #pragma unroll
  for (int nt=0; nt<4; ++nt) b1v[nt] = b1[nt*16 + m];

  for (int stepi=0; stepi<4; ++stepi){
    f32x4 acc[4];
    #pragma unroll
    for (int b=0;b<4;++b) acc[b] = 0.f;
    #pragma unroll
    for (int kk=0; kk<8; ++kk){
      const int ko = kk*32;
      short8 af = *(const short8*)&At[abase + ko];
      short8 bf[4];
      #pragma unroll
      for (int nt=0; nt<4; ++nt) bf[nt] = *(const short8*)&Ws[bbase[nt] + ko];
      #pragma unroll
      for (int nt=0; nt<4; ++nt)
        acc[nt] = __builtin_amdgcn_mfma_f32_16x16x32_bf16(af, bf[nt], acc[nt], 0,0,0);
    }
    #pragma unroll
    for (int nt=0; nt<4; ++nt){
      #pragma unroll
      for (int r=0; r<4; ++r){
        int px = wave*16 + quad*4 + r;
        At[px*264 + stepi*64 + nt*16 + m] = f2bf(acc[nt][r] + b1v[nt]);
      }
    }
    // no barrier: each wave reads/writes only its own 16 px
  }
  __syncthreads();
  #pragma unroll
  for (int it=0; it<16; ++it){
    int idx = it*256 + tid;
    int px = idx >> 6;
    int c4 = (idx & 63) << 2;
    uint2 v = *(const uint2*)&At[px*264 + c4];
    v.x = relu_pk(v.x); v.y = relu_pk(v.y);
    *(uint2*)&B[(pbase + px)*CH + c4] = v;
  }
}

// ---------------- phase 2: one 3x3 gradual-update step (launched 4x) ----------------
// 16x16 px tiles, 256 blocks, 512 threads (8 waves = 2/SIMD).
// Wave tile 32px x 64ch (mt=2: rows w, w+8; nt=4). acc = 32 VGPR (no spill).
// As single-buffered per 64-ch quarter (46.7 KB); Ws double-buffered (2x27 KB).
__global__ __launch_bounds__(512) void k_phase2(const u16* __restrict__ B,
    u16* __restrict__ Bout, const u16* __restrict__ W2T, const float* __restrict__ b2,
    const int step){
  __shared__ u16 As[324*72];      // 18x18 halo px x 64 ch (+8 pad)  46656 B
  __shared__ u16 Ws[2][192*72];   // [dc][n] x 64 ch (+8 pad)        2x27648 B
  const int tid = threadIdx.x;
  const int bid = blockIdx.x;
  const int img = bid >> 4;
  const int R0 = ((bid >> 2) & 3) * 16;
  const int C0 = (bid & 3) * 16;

  const int wave = tid >> 6, lane = tid & 63;
  const int m = lane & 15, quad = lane >> 4;

  uint4 ra[6], rw[3];

  auto load_as = [&](int q, uint4* r4){
    #pragma unroll
    for (int it=0; it<6; ++it){
      int idx = it*512 + tid;
      uint4 v = make_uint4(0u,0u,0u,0u);
      if (idx < 2592){
        int px = idx >> 3, ck = idx & 7;
        int hr = px / 18, hc = px - hr*18;
        int r = R0 + hr - 1, c = C0 + hc - 1;
        if ((unsigned)r < 64u && (unsigned)c < 64u){
          const u16* src = (q < step) ? Bout : B;   // B already relu'd by phase1
          v = *(const uint4*)&src[((((size_t)img*64)+r)*64 + c)*CH + q*64 + ck*8];
        }
      }
      r4[it] = v;
    }
  };
  auto store_as = [&](const uint4* r4){
    #pragma unroll
    for (int it=0; it<6; ++it){
      int idx = it*512 + tid;
      if (idx < 2592){
        int px = idx >> 3, ck = idx & 7;
        *(uint4*)&As[px*72 + ck*8] = r4[it];
      }
    }
  };
  auto load_ws = [&](int q, int dr, uint4* r4){
    #pragma unroll
    for (int it=0; it<3; ++it){
      int idx = it*512 + tid;                  // 1536 exact
      int row = idx >> 3, ck = idx & 7;        // row = dc*64 + n
      int dc = row >> 6, n = row & 63;
      r4[it] = *(const uint4*)&W2T[(size_t)n*2304 + (dr*3 + dc)*256 + q*64 + ck*8];
    }
  };
  auto store_ws = [&](int buf, const uint4* r4){
    #pragma unroll
    for (int it=0; it<3; ++it){
      int idx = it*512 + tid;
      int row = idx >> 3, ck = idx & 7;
      *(uint4*)&Ws[buf][row*72 + ck*8] = r4[it];
    }
  };

  // prologue
  load_ws(0, 0, rw); store_ws(0, rw);
  load_as(0, ra);    store_as(ra);
  __syncthreads();

  f32x4 acc[2][4];
  #pragma unroll
  for (int a=0;a<2;++a){
    #pragma unroll
    for (int b=0;b<4;++b) acc[a][b] = 0.f;
  }

  int seg = 0;
  for (int q = 0; q < 4; ++q){
    for (int dr = 0; dr < 3; ++dr, ++seg){
      const int wb = seg & 1;
      const bool pfW = (seg < 11);
      if (dr < 2)      load_ws(q, dr+1, rw);
      else if (q < 3)  load_ws(q+1, 0, rw);
      const bool pfA = (dr == 2) && (q < 3);
      if (pfA) load_as(q+1, ra);

      const u16* wsb = Ws[wb];
      #pragma unroll
      for (int dc=0; dc<3; ++dc){
        #pragma unroll
        for (int kk=0; kk<2; ++kk){
          short8 af[2], bf[4];
          #pragma unroll
          for (int mt=0; mt<2; ++mt){
            int rt = wave + mt*8;
            af[mt] = *(const short8*)&As[((rt+dr)*18 + m + dc)*72 + kk*32 + quad*8];
          }
          #pragma unroll
          for (int nt=0; nt<4; ++nt)
            bf[nt] = *(const short8*)&wsb[(dc*64 + nt*16 + m)*72 + kk*32 + quad*8];
          #pragma unroll
          for (int mt=0; mt<2; ++mt){
            #pragma unroll
            for (int nt=0; nt<4; ++nt)
              acc[mt][nt] = __builtin_amdgcn_mfma_f32_16x16x32_bf16(af[mt], bf[nt], acc[mt][nt], 0,0,0);
          }
        }
      }
      if (pfW) store_ws(wb^1, rw);
      if (pfA){ __syncthreads(); store_as(ra); }
      __syncthreads();
    }
  }

  float b2v[4];
  #pragma unroll
  for (int nt=0; nt<4; ++nt) b2v[nt] = b2[nt*16 + m];
  #pragma unroll
  for (int mt=0; mt<2; ++mt){
    #pragma unroll
    for (int nt=0; nt<4; ++nt){
      #pragma unroll
      for (int r=0; r<4; ++r){
        int row = R0 + wave + mt*8;
        int col = C0 + quad*4 + r;
        size_t gi = ((((size_t)img*64 + row)*64) + col)*CH + step*64 + nt*16 + m;
        Bout[gi] = f2bf(acc[mt][nt][r] + b2v[nt]);
      }
    }
  }
}

// ---------------- phase 3: per-pixel affine recurrence + residual ----------------
// Thread pair splits a pixel's 256 channels (h=0: 0..127, h=1: 128..255).
// A'_{i+1} = (1+w_i)A'_i - w_i a_i  is affine in A'_0: prefix (alpha,beta) per half.
// Register-resident, grid 512 (2 waves/SIMD). fp32 output (no extra bf16 round).
__global__ __launch_bounds__(256) void k_phase3(const u16* __restrict__ Bout,
    const float* __restrict__ w3, const float* __restrict__ b3,
    const float* __restrict__ x, float* __restrict__ out){
  __shared__ float w3s[256];
  const int tid = threadIdx.x;
  if (tid < 64) *(float4*)&w3s[tid*4] = *(const float4*)&w3[tid*4];
  const float b3v = b3[0];
  __syncthreads();

  const int g  = blockIdx.x*256 + tid;
  const int px = g >> 1;
  const int h  = g & 1;
  const size_t cbase = (size_t)px*CH + h*128;

  // load own 128 channels (relu'd), keep in registers
  uint4 d[16];
  #pragma unroll
  for (int i=0; i<16; ++i){
    uint4 v = *(const uint4*)&Bout[cbase + i*8];
    v.x = relu_pk(v.x); v.y = relu_pk(v.y); v.z = relu_pk(v.z); v.w = relu_pk(v.w);
    d[i] = v;
  }

  // partial dot product over own half
  float s0=0.f, s1=0.f;
  #pragma unroll
  for (int i=0; i<16; ++i){
    const u32* p = (const u32*)&d[i];
    #pragma unroll
    for (int k=0; k<4; ++k){
      u32 w = p[k];
      int c = i*8 + k*2;
      s0 += bf2f((u16)(w & 0xFFFF))  * w3s[h*128 + c];
      s1 += bf2f((u16)(w >> 16))     * w3s[h*128 + c + 1];
    }
  }
  float dot = s0 + s1;
  float tot = b3v + dot + __shfl_xor(dot, 1);   // A'_0 (same at both lanes of pair)

  // affine prefix over own half: A'_end = alpha*A'_start + beta
  float alpha = 1.f, beta = 0.f;
  #pragma unroll
  for (int i=0; i<16; ++i){
    const u32* p = (const u32*)&d[i];
    #pragma unroll
    for (int k=0; k<4; ++k){
      u32 wv = p[k];
      int c = i*8 + k*2;
      float w_a = w3s[h*128 + c];
      float w_b = w3s[h*128 + c + 1];
      float a_a = bf2f((u16)(wv & 0xFFFF));
      float a_b = bf2f((u16)(wv >> 16));
      beta  = (1.f + w_a)*beta  - w_a*a_a;
      alpha = (1.f + w_a)*alpha;
      beta  = (1.f + w_b)*beta  - w_b*a_b;
      alpha = (1.f + w_b)*alpha;
    }
  }
  float al_o = __shfl_xor(alpha, 1);
  float be_o = __shfl_xor(beta, 1);
  float Ap = (h == 0) ? tot : (al_o*tot + be_o);

  // output pass: out_c = A'_c + x_c ; A' <- (1+w)A' - w*a
  #pragma unroll
  for (int i=0; i<16; ++i){
    const u32* p = (const u32*)&d[i];
    float4 xv0 = *(const float4*)&x[cbase + i*8];
    float4 xv1 = *(const float4*)&x[cbase + i*8 + 4];
    float4 o0, o1;
    float xs[8] = {xv0.x,xv0.y,xv0.z,xv0.w,xv1.x,xv1.y,xv1.z,xv1.w};
    float os[8];
    #pragma unroll
    for (int k=0; k<4; ++k){
      u32 wv = p[k];
      int c = i*8 + k*2;
      float w_a = w3s[h*128 + c];
      float w_b = w3s[h*128 + c + 1];
      float a_a = bf2f((u16)(wv & 0xFFFF));
      float a_b = bf2f((u16)(wv >> 16));
      os[k*2]   = Ap + xs[k*2];
      Ap = (1.f + w_a)*Ap - w_a*a_a;
      os[k*2+1] = Ap + xs[k*2+1];
      Ap = (1.f + w_b)*Ap - w_b*a_b;
    }
    o0.x=os[0]; o0.y=os[1]; o0.z=os[2]; o0.w=os[3];
    o1.x=os[4]; o1.y=os[5]; o1.z=os[6]; o1.w=os[7];
    *(float4*)&out[cbase + i*8]     = o0;
    *(float4*)&out[cbase + i*8 + 4] = o1;
  }
}

extern "C" void kernel_launch(void* const* d_in, const int* in_sizes, int n_in,
                              void* d_out, int out_size, void* d_ws, size_t ws_size,
                              hipStream_t stream){
  const float* x  = (const float*)d_in[0];
  const float* w1 = (const float*)d_in[1];
  const float* b1 = (const float*)d_in[2];
  const float* w2 = (const float*)d_in[3];
  const float* b2 = (const float*)d_in[4];
  const float* w3 = (const float*)d_in[5];
  const float* b3 = (const float*)d_in[6];
  float* out = (float*)d_out;

  // workspace carve: B(relu'd) 32MB | Bout 32MB | W1T 32KB | W2T 288KB
  u16* B    = (u16*)d_ws;
  u16* Bout = B    + (size_t)NPIX*CH;
  u16* W1T  = Bout + (size_t)NPIX*CH;
  u16* W2T  = W1T  + 16384;

  hipLaunchKernelGGL(k_prep,   dim3(640),  dim3(256), 0, stream, w1, w2, W1T, W2T);
  hipLaunchKernelGGL(k_phase1, dim3(1024), dim3(256), 0, stream, x, W1T, b1, B);
  for (int s = 0; s < 4; ++s)
    hipLaunchKernelGGL(k_phase2, dim3(256), dim3(512), 0, stream, B, Bout, W2T, b2, s);
  hipLaunchKernelGGL(k_phase3, dim3(512), dim3(256), 0, stream, Bout, w3, b3, x, out);
}